// Round 1
// 1288.531 us; speedup vs baseline: 1.0529x; 1.0529x over previous
//
#include <hip/hip_runtime.h>
#include <cstdint>
#include <cstddef>

#define EPI_NONE 0
#define EPI_SILU 1
#define EPI_LOGSIG 2

typedef __attribute__((ext_vector_type(8))) short bf16x8;
typedef __attribute__((ext_vector_type(4))) float f32x4;

// ---- bf16 helpers on raw ushort ----
__device__ __forceinline__ float us2f(unsigned short u) {
    unsigned int x = ((unsigned int)u) << 16;
    return __uint_as_float(x);
}
__device__ __forceinline__ unsigned short f2us(float f) {
    unsigned int x = __float_as_uint(f);
    unsigned int r = (x + 0x7fffu + ((x >> 16) & 1u)) >> 16;
    return (unsigned short)r;
}

// async global->LDS, 16 bytes per lane; LDS dest = wave-uniform base + lane*16
__device__ __forceinline__ void gl_lds16(const unsigned short* g, unsigned short* l) {
    __builtin_amdgcn_global_load_lds(
        (const __attribute__((address_space(1))) void*)g,
        (__attribute__((address_space(3))) void*)l, 16, 0, 0);
}

// raw barrier (no implicit vmcnt/lgkm drain, unlike __syncthreads)
#define BARR() asm volatile("s_barrier" ::: "memory")
#define LGKM0() do { asm volatile("s_waitcnt lgkmcnt(0)" ::: "memory"); \
                     __builtin_amdgcn_sched_barrier(0); } while (0)
#define VMCNT(n) do { asm volatile("s_waitcnt vmcnt(" #n ")" ::: "memory"); \
                      __builtin_amdgcn_sched_barrier(0); } while (0)

template<int EPI>
__device__ __forceinline__ float act(float z) {
    if constexpr (EPI == EPI_SILU) {
        return z / (1.f + __expf(-z));
    } else if constexpr (EPI == EPI_LOGSIG) {
        float s = 1.f / (1.f + __expf(-z));
        return -log1pf(__expf(-s));
    }
    return z;
}

// =============== cast fp32 -> bf16, 8 elems/thread ===============
__global__ __launch_bounds__(256) void cast_bf16(const float* __restrict__ in,
                                                 unsigned short* __restrict__ out, int n8)
{
    int i = blockIdx.x * blockDim.x + threadIdx.x;
    if (i >= n8) return;
    const float4* p = (const float4*)(in + (size_t)i * 8);
    float4 a = p[0], b = p[1];
    __align__(16) unsigned short u[8];
    u[0] = f2us(a.x); u[1] = f2us(a.y); u[2] = f2us(a.z); u[3] = f2us(a.w);
    u[4] = f2us(b.x); u[5] = f2us(b.y); u[6] = f2us(b.z); u[7] = f2us(b.w);
    *(uint4*)(out + (size_t)i * 8) = *(const uint4*)u;
}

// ---- fragment loads from XOR-swizzled [256][64] LDS tile ----
__device__ __forceinline__ void ld_a4(bf16x8 d[4][2], const unsigned short* buf,
                                      int rowbase, int fr, int fq, int rx)
{
#pragma unroll
    for (int t = 0; t < 4; ++t) {
        const int row = rowbase + t * 16 + fr;
#pragma unroll
        for (int ks = 0; ks < 2; ++ks)
            d[t][ks] = *(const bf16x8*)&buf[row * 64 + ((((ks << 2) + fq) ^ rx) << 3)];
    }
}
__device__ __forceinline__ void ld_b2(bf16x8 d[2][2], const unsigned short* buf,
                                      int rowbase, int fr, int fq, int rx)
{
#pragma unroll
    for (int t = 0; t < 2; ++t) {
        const int row = rowbase + t * 16 + fr;
#pragma unroll
        for (int ks = 0; ks < 2; ++ks)
            d[t][ks] = *(const bf16x8*)&buf[row * 64 + ((((ks << 2) + fq) ^ rx) << 3)];
    }
}
__device__ __forceinline__ void mma_q(f32x4 acc[8][4], const bf16x8 a[4][2], const bf16x8 b[2][2],
                                      int ti0, int tj0)
{
#pragma unroll
    for (int ks = 0; ks < 2; ++ks)
#pragma unroll
        for (int i = 0; i < 4; ++i)
#pragma unroll
            for (int j = 0; j < 2; ++j)
                acc[ti0 + i][tj0 + j] = __builtin_amdgcn_mfma_f32_16x16x32_bf16(
                    a[i][ks], b[j][ks], acc[ti0 + i][tj0 + j], 0, 0, 0);
}

// =============== bf16 MFMA GEMM v3: 256x256 tile, BK=64, 8-phase counted-vmcnt ===============
// C[M,N] = act(A[M,K] * B[N,K]^T). 512 threads = 8 waves (2M x 4N), per-wave 128x64 out.
// LDS 128 KiB: double-buffered A/B K-tiles, XOR-swizzled (conflict-free ds_read_b128).
// Schedule (per K-tile T, 4 phases; vmcnt never drained to 0 in steady state):
//   ph1: ds A-lo(8)+B-lo(4) | stage (T+1,A1) | bar | lgkm0 | 16 mfma q0 | bar
//   ph2: ds B-hi(4)         |                | bar | lgkm0 | 16 mfma q1 | bar
//   ph3: ds A-hi(8)         | stage (T+2,B0) | bar | lgkm0 | 16 mfma q2 | bar
//   ph4:                    | stage (T+2,B1),(T+2,A0) | vmcnt(6) | bar | lgkm0 | 16 mfma q3 | bar
// Race-safety: B-halves of the live buffer are dead after ph2, A-halves after ph3;
// T+2 stages (same buffer as T) are issued only after their region's last read phase.
// vmcnt(6) tail = the 3 T+2 halves => all of T+1 resident before its ph1 reads.
template<int EPI, bool OUT_BF16>
__global__ __launch_bounds__(512, 2) void gemm_bt_mfma(const unsigned short* __restrict__ A,
                                                       const unsigned short* __restrict__ B,
                                                       void* __restrict__ Cv,
                                                       int M, int N, int K)
{
    __shared__ unsigned short smem[65536];        // 128 KB: [As0|Bs0|As1|Bs1] x 16384 elems

    const int tid  = threadIdx.x;
    const int lane = tid & 63;
    const int wv   = tid >> 6;                    // 0..7
    const int m0   = blockIdx.x * 256;
    const int n0   = blockIdx.y * 256;
    const int wr   = (wv >> 2) * 128;             // 0 | 128
    const int wc   = (wv & 3) * 64;               // 0 | 64 | 128 | 192
    const int fr   = lane & 15;
    const int fq   = lane >> 4;
    const int rx   = fr & 7;
    const int NT   = K >> 6;

    unsigned short* const As0 = smem;
    unsigned short* const Bs0 = smem + 16384;
    unsigned short* const As1 = smem + 32768;
    unsigned short* const Bs1 = smem + 49152;

    // staging: per half-tile (128 rows x 64 cols) 2 instrs; wave w owns rows w*8..w*8+7 of
    // each 64-row instr-block. lane l: row-in-group l>>3, source k-chunk (l&7)^(l>>3)
    // (pre-swizzled global source, linear LDS dest -> swizzled tile).
    const int srow = wv * 8 + (lane >> 3);
    const int scol = ((lane & 7) ^ (lane >> 3)) << 3;
    const unsigned short* Ag[2][2];
    const unsigned short* Bg[2][2];
#pragma unroll
    for (int h = 0; h < 2; ++h)
#pragma unroll
        for (int i = 0; i < 2; ++i) {
            Ag[h][i] = A + (size_t)(m0 + h * 128 + i * 64 + srow) * K + scol;
            Bg[h][i] = B + (size_t)(n0 + h * 128 + i * 64 + srow) * K + scol;
        }

#define STAGE(gb, lb, h, Tt) do {                                         \
        unsigned short* _l = (lb) + (h) * 8192 + wv * 512;                \
        gl_lds16(gb[h][0] + (size_t)(Tt) * 64, _l);                       \
        gl_lds16(gb[h][1] + (size_t)(Tt) * 64, _l + 4096);                \
    } while (0)

    f32x4 acc[8][4];
#pragma unroll
    for (int i = 0; i < 8; ++i)
#pragma unroll
        for (int j = 0; j < 4; ++j) acc[i][j] = (f32x4){0.f, 0.f, 0.f, 0.f};

    bf16x8 af[4][2], b0[2][2], b1[2][2];

    // ---- prologue: tile0 full + tile1 {B0,B1,A0}; A1 of tile1 is staged in T=0 ph1 ----
    STAGE(Ag, As0, 0, 0); STAGE(Ag, As0, 1, 0);
    STAGE(Bg, Bs0, 0, 0); STAGE(Bg, Bs0, 1, 0);
    STAGE(Bg, Bs1, 0, 1); STAGE(Bg, Bs1, 1, 1);
    STAGE(Ag, As1, 0, 1);
    VMCNT(6);                                     // tile0 resident; 3 halves in flight
    BARR();

    for (int T = 0; T < NT; ++T) {
        const int pb = T & 1;
        unsigned short* const Ab  = smem + pb * 32768;
        unsigned short* const Bb  = Ab + 16384;
        unsigned short* const Anx = smem + (pb ^ 1) * 32768;

        // ---- phase 1: q0 = A-lo x B-lo ----
        ld_a4(af, Ab, wr, fr, fq, rx);
        ld_b2(b0, Bb, wc, fr, fq, rx);
        if (T + 1 < NT) STAGE(Ag, Anx, 1, T + 1);
        BARR(); LGKM0();
        __builtin_amdgcn_s_setprio(1);
        mma_q(acc, af, b0, 0, 0);
        __builtin_amdgcn_s_setprio(0);
        BARR();

        // ---- phase 2: q1 = A-lo x B-hi ----
        ld_b2(b1, Bb, wc + 32, fr, fq, rx);
        BARR(); LGKM0();
        __builtin_amdgcn_s_setprio(1);
        mma_q(acc, af, b1, 0, 2);
        __builtin_amdgcn_s_setprio(0);
        BARR();

        // ---- phase 3: q2 = A-hi x B-lo ----
        ld_a4(af, Ab, wr + 64, fr, fq, rx);
        if (T + 2 < NT) STAGE(Bg, Bb, 0, T + 2);   // B0 region dead since ph2-end
        BARR(); LGKM0();
        __builtin_amdgcn_s_setprio(1);
        mma_q(acc, af, b0, 4, 0);
        __builtin_amdgcn_s_setprio(0);
        BARR();

        // ---- phase 4: q3 = A-hi x B-hi ----
        if (T + 2 < NT) { STAGE(Bg, Bb, 1, T + 2); STAGE(Ag, Ab, 0, T + 2); }
        if (T + 2 < NT)      { VMCNT(6); }         // forces all of tile T+1 resident
        else if (T + 1 < NT) { VMCNT(0); }         // last prefetched tile: full drain
        BARR(); LGKM0();
        __builtin_amdgcn_s_setprio(1);
        mma_q(acc, af, b1, 4, 2);
        __builtin_amdgcn_s_setprio(0);
        BARR();
    }
#undef STAGE

    // C/D layout: col = lane&15, row = (lane>>4)*4 + reg
    const int crow = fq * 4;
    const int ccol = fr;

    if (OUT_BF16) {
        VMCNT(0);                                  // nothing should be in flight; belt+braces
        unsigned short* Cs = smem;                 // [128][264] per half
        // ---- half 0 (rows m0..m0+127): waves wr==0 hold all of it ----
        if (wr == 0) {
#pragma unroll
            for (int ti = 0; ti < 8; ++ti)
#pragma unroll
                for (int r = 0; r < 4; ++r)
#pragma unroll
                    for (int tj = 0; tj < 4; ++tj)
                        Cs[(ti * 16 + crow + r) * 264 + wc + tj * 16 + ccol] =
                            f2us(act<EPI>(acc[ti][tj][r]));
        }
        LGKM0(); BARR();
        {
            const int row = tid >> 2, cb = (tid & 3) << 6;
            const unsigned short* src = &Cs[row * 264 + cb];
            unsigned short* dst = (unsigned short*)Cv + (size_t)(m0 + row) * N + n0 + cb;
#pragma unroll
            for (int j = 0; j < 8; ++j)
                *(uint4*)(dst + j * 8) = *(const uint4*)(src + j * 8);
        }
        BARR();
        // ---- half 1 (rows m0+128..m0+255): waves wr==128 ----
        if (wr == 128) {
#pragma unroll
            for (int ti = 0; ti < 8; ++ti)
#pragma unroll
                for (int r = 0; r < 4; ++r)
#pragma unroll
                    for (int tj = 0; tj < 4; ++tj)
                        Cs[(ti * 16 + crow + r) * 264 + wc + tj * 16 + ccol] =
                            f2us(act<EPI>(acc[ti][tj][r]));
        }
        LGKM0(); BARR();
        {
            const int row = tid >> 2, cb = (tid & 3) << 6;
            const unsigned short* src = &Cs[row * 264 + cb];
            unsigned short* dst = (unsigned short*)Cv + (size_t)(m0 + 128 + row) * N + n0 + cb;
#pragma unroll
            for (int j = 0; j < 8; ++j)
                *(uint4*)(dst + j * 8) = *(const uint4*)(src + j * 8);
        }
    } else {
        float* C = (float*)Cv;
#pragma unroll
        for (int ti = 0; ti < 8; ++ti)
#pragma unroll
            for (int r = 0; r < 4; ++r) {
                const int row = m0 + wr + ti * 16 + crow + r;
#pragma unroll
                for (int tj = 0; tj < 4; ++tj)
                    C[(size_t)row * N + n0 + wc + tj * 16 + ccol] = act<EPI>(acc[ti][tj][r]);
            }
    }
}

// =============== GLA pass A1: decays + scores + intra (per chunk,bh) ===============
__global__ __launch_bounds__(256) void gla_a1(unsigned short* __restrict__ qb,
                                              unsigned short* __restrict__ lfb,
                                              const unsigned short* __restrict__ vb,
                                              unsigned short* __restrict__ obf,
                                              float* __restrict__ dbuf)
{
    __shared__ unsigned short q_sh[64][136];
    __shared__ unsigned short kd_sh[64][136];
    __shared__ unsigned short vT[128][72];   // v^T [f][t]
    __shared__ unsigned short sc[64][72];    // scores [t][s]

    const int tid = threadIdx.x;
    const int bid = blockIdx.x;
    const int c = bid >> 6, bh = bid & 63;
    const int b = bh >> 4, h = bh & 15;
    const size_t tok0 = ((size_t)b * 4096 + (size_t)c * 64) * 2048 + (size_t)h * 128;

#pragma unroll
    for (int k = 0; k < 4; ++k) {
        int vi = tid + k * 256;
        int t = vi >> 4, e8 = (vi & 15) << 3;
        *(uint4*)&q_sh[t][e8]  = *(const uint4*)(qb  + tok0 + (size_t)t * 2048 + e8);
        *(uint4*)&kd_sh[t][e8] = *(const uint4*)(lfb + tok0 + (size_t)t * 2048 + e8);
    }
    if (tid < 128) {
        int t8 = tid >> 4, f8 = tid & 15;
        __align__(16) unsigned short a[8][8];
#pragma unroll
        for (int r = 0; r < 8; ++r)
            *(uint4*)a[r] = *(const uint4*)(vb + tok0 + (size_t)(t8 * 8 + r) * 2048 + f8 * 8);
#pragma unroll
        for (int j = 0; j < 8; ++j) {
            __align__(16) unsigned short w8[8];
#pragma unroll
            for (int r = 0; r < 8; ++r) w8[r] = a[r][j];
            *(uint4*)&vT[f8 * 8 + j][t8 * 8] = *(const uint4*)w8;
        }
    }
    __syncthreads();
    if (tid < 128) {
        const int e = tid;
        float a = 0.f;
        for (int t = 0; t < 64; ++t) {
            float lf = us2f(kd_sh[t][e]);
            a += lf;
            q_sh[t][e]  = f2us(us2f(q_sh[t][e]) * __expf(a));       // q_dec
            kd_sh[t][e] = f2us((1.f - __expf(lf)) * __expf(-a));    // k_dec
        }
        dbuf[(size_t)bid * 128 + e] = __expf(a);
    }
    __syncthreads();
#pragma unroll
    for (int k = 0; k < 4; ++k) {
        int vi = tid + k * 256;
        int t = vi >> 4, e8 = (vi & 15) << 3;
        *(uint4*)(qb  + tok0 + (size_t)t * 2048 + e8) = *(const uint4*)&q_sh[t][e8];
        *(uint4*)(lfb + tok0 + (size_t)t * 2048 + e8) = *(const uint4*)&kd_sh[t][e8];
    }

    const int lane = tid & 63, w = tid >> 6;
    const int fr = lane & 15, fq = lane >> 4;

    // scores = qdec @ kdec^T
    f32x4 sacc[4];
#pragma unroll
    for (int j = 0; j < 4; ++j) sacc[j] = (f32x4){0.f, 0.f, 0.f, 0.f};
#pragma unroll
    for (int ke = 0; ke < 4; ++ke) {
        bf16x8 af = *(const bf16x8*)&q_sh[16 * w + fr][ke * 32 + fq * 8];
#pragma unroll
        for (int tj = 0; tj < 4; ++tj) {
            bf16x8 bfv = *(const bf16x8*)&kd_sh[16 * tj + fr][ke * 32 + fq * 8];
            sacc[tj] = __builtin_amdgcn_mfma_f32_16x16x32_bf16(af, bfv, sacc[tj], 0, 0, 0);
        }
    }
#pragma unroll
    for (int tj = 0; tj < 4; ++tj)
#pragma unroll
        for (int r = 0; r < 4; ++r) {
            int trow = 16 * w + fq * 4 + r;
            int scol = 16 * tj + fr;
            sc[trow][scol] = f2us(scol <= trow ? sacc[tj][r] : 0.f);
        }
    __syncthreads();
    // intra = sc @ v
    f32x4 oacc[8];
#pragma unroll
    for (int j = 0; j < 8; ++j) oacc[j] = (f32x4){0.f, 0.f, 0.f, 0.f};
#pragma unroll
    for (int ks = 0; ks < 2; ++ks) {
        bf16x8 af = *(const bf16x8*)&sc[16 * w + fr][ks * 32 + fq * 8];
#pragma unroll
        for (int tf = 0; tf < 8; ++tf) {
            bf16x8 bfv = *(const bf16x8*)&vT[16 * tf + fr][ks * 32 + fq * 8];
            oacc[tf] = __builtin_amdgcn_mfma_f32_16x16x32_bf16(af, bfv, oacc[tf], 0, 0, 0);
        }
    }
#pragma unroll
    for (int tf = 0; tf < 8; ++tf) {
        __align__(8) unsigned short o4[4];
#pragma unroll
        for (int r = 0; r < 4; ++r) o4[r] = f2us(oacc[tf][r]);
        *(uint2*)(obf + (((size_t)bid * 4 + w) * 8 + tf) * 256 + lane * 4) = *(const uint2*)o4;
    }
}

// =============== GLA pass A2: U^T[f][e] = d[e] * sum_t kdec[t][e] v[t][f] ===============
__global__ __launch_bounds__(256) void gla_a2(const unsigned short* __restrict__ lfb, // kdec
                                              const unsigned short* __restrict__ vb,
                                              const float* __restrict__ dbuf,
                                              unsigned short* __restrict__ UT)
{
    __shared__ unsigned short vT[128][72];
    __shared__ unsigned short kdT[128][72];
    __shared__ float d_sh[128];

    const int tid = threadIdx.x;
    const int bid = blockIdx.x;
    const int c = bid >> 6, bh = bid & 63;
    const int b = bh >> 4, h = bh & 15;
    const size_t tok0 = ((size_t)b * 4096 + (size_t)c * 64) * 2048 + (size_t)h * 128;

    if (tid < 128) {
        int t8 = tid >> 4, f8 = tid & 15;
        __align__(16) unsigned short a[8][8];
#pragma unroll
        for (int r = 0; r < 8; ++r)
            *(uint4*)a[r] = *(const uint4*)(vb + tok0 + (size_t)(t8 * 8 + r) * 2048 + f8 * 8);
#pragma unroll
        for (int j = 0; j < 8; ++j) {
            __align__(16) unsigned short w8[8];
#pragma unroll
            for (int r = 0; r < 8; ++r) w8[r] = a[r][j];
            *(uint4*)&vT[f8 * 8 + j][t8 * 8] = *(const uint4*)w8;
        }
        d_sh[tid] = dbuf[(size_t)bid * 128 + tid];
    } else {
        int i = tid - 128;
        int t8 = i >> 4, e8b = i & 15;
        __align__(16) unsigned short a[8][8];
#pragma unroll
        for (int r = 0; r < 8; ++r)
            *(uint4*)a[r] = *(const uint4*)(lfb + tok0 + (size_t)(t8 * 8 + r) * 2048 + e8b * 8);
#pragma unroll
        for (int j = 0; j < 8; ++j) {
            __align__(16) unsigned short w8[8];
#pragma unroll
            for (int r = 0; r < 8; ++r) w8[r] = a[r][j];
            *(uint4*)&kdT[e8b * 8 + j][t8 * 8] = *(const uint4*)w8;
        }
    }
    __syncthreads();

    const int lane = tid & 63, w = tid >> 6;
    const int fr = lane & 15, fq = lane >> 4;

    f32x4 acc[2][8];
#pragma unroll
    for (int mi = 0; mi < 2; ++mi)
#pragma unroll
        for (int te = 0; te < 8; ++te) acc[mi][te] = (f32x4){0.f, 0.f, 0.f, 0.f};
#pragma unroll
    for (int kt = 0; kt < 2; ++kt) {
        bf16x8 af0 = *(const bf16x8*)&vT[16 * (2 * w + 0) + fr][kt * 32 + fq * 8];
        bf16x8 af1 = *(const bf16x8*)&vT[16 * (2 * w + 1) + fr][kt * 32 + fq * 8];
#pragma unroll
        for (int te = 0; te < 8; ++te) {
            bf16x8 bfv = *(const bf16x8*)&kdT[16 * te + fr][kt * 32 + fq * 8];
            acc[0][te] = __builtin_amdgcn_mfma_f32_16x16x32_bf16(af0, bfv, acc[0][te], 0, 0, 0);
            acc[1][te] = __builtin_amdgcn_mfma_f32_16x16x32_bf16(af1, bfv, acc[1][te], 0, 0, 0);
        }
    }
    unsigned short* up = UT + (size_t)bid * 16384;
#pragma unroll
    for (int mi = 0; mi < 2; ++mi)
#pragma unroll
        for (int te = 0; te < 8; ++te) {
            int e = 16 * te + fr;
            float dv = d_sh[e];
#pragma unroll
            for (int r = 0; r < 4; ++r) {
                int f = 32 * w + 16 * mi + fq * 4 + r;
                up[f * 128 + e] = f2us(acc[mi][te][r] * dv);
            }
        }
}

// =============== GLA pass B: in-place scan UT[c] -> S-before-chunk-c ===============
__global__ __launch_bounds__(256) void gla_scan(unsigned short* __restrict__ UT,
                                                const float* __restrict__ dbuf)
{
    const int tid = threadIdx.x;
    const int bh = blockIdx.x >> 3, fs = blockIdx.x & 7;
    const int f = fs * 16 + (tid >> 4);
    const int e8 = (tid & 15) << 3;
    float S[8];
#pragma unroll
    for (int j = 0; j < 8; ++j) S[j] = 0.f;
    for (int c = 0; c < 64; ++c) {
        const size_t cb = (size_t)(c * 64 + bh);
        const size_t loc = cb * 16384 + (size_t)f * 128 + e8;
        uint4 uu = *(const uint4*)(UT + loc);
        float4 d0 = *(const float4*)(dbuf + cb * 128 + e8);
        float4 d1 = *(const float4*)(dbuf + cb * 128 + e8 + 4);
        __align__(16) unsigned short us8[8];
        *(uint4*)us8 = uu;
        __align__(16) unsigned short so[8];
#pragma unroll
        for (int j = 0; j < 8; ++j) so[j] = f2us(S[j]);
        *(uint4*)(UT + loc) = *(const uint4*)so;
        float dd[8] = {d0.x, d0.y, d0.z, d0.w, d1.x, d1.y, d1.z, d1.w};
#pragma unroll
        for (int j = 0; j < 8; ++j) S[j] = fmaf(dd[j], S[j], us2f(us8[j]));
    }
}

// =============== GLA pass C: o = intra + qdec @ S^T; write o over qb ===============
__global__ __launch_bounds__(256) void gla_c(unsigned short* __restrict__ qb,
                                             const unsigned short* __restrict__ UT, // = S^T[f][e]
                                             const unsigned short* __restrict__ obf)
{
    __shared__ unsigned short q_sh[64][136];
    __shared__ unsigned short ST_sh[128][136];

    const int tid = threadIdx.x;
    const int bid = blockIdx.x;
    const int c = bid >> 6, bh = bid & 63;
    const int b = bh >> 4, h = bh & 15;
    const size_t tok0 = ((size_t)b * 4096 + (size_t)c * 64) * 2048 + (size_t)h * 128;

#pragma unroll
    for (int k = 0; k < 4; ++k) {
        int vi = tid + k * 256;
        int t = vi >> 4, e8 = (vi & 15) << 3;
        *(uint4*)&q_sh[t][e8] = *(const uint4*)(qb + tok0 + (size_t)t * 2048 + e8);
    }
    const unsigned short* stp = UT + (size_t)bid * 16384;
#pragma unroll
    for (int k = 0; k < 8; ++k) {
        int vi = tid + k * 256;
        int f = vi >> 4, e8 = (vi & 15) << 3;
        *(uint4*)&ST_sh[f][e8] = *(const uint4*)(stp + (size_t)f * 128 + e8);
    }
    const int lane = tid & 63, w = tid >> 6;
    const int fr = lane & 15, fq = lane >> 4;

    f32x4 acc[8];
#pragma unroll
    for (int tf = 0; tf < 8; ++tf) {
        uint2 iv = *(const uint2*)(obf + (((size_t)bid * 4 + w) * 8 + tf) * 256 + lane * 4);
        __align__(8) unsigned short s4[4];
        *(uint2*)s4 = iv;
        acc[tf] = (f32x4){us2f(s4[0]), us2f(s4[1]), us2f(s4[2]), us2f(s4[3])};
    }
    __syncthreads();
#pragma unroll
    for (int ke = 0; ke < 4; ++ke) {
        bf16x8 af = *(const bf16x8*)&q_sh[16 * w + fr][ke * 32 + fq * 8];
#pragma unroll
        for (int tf = 0; tf < 8; ++tf) {
            bf16x8 bfv = *(const bf16x8*)&ST_sh[16 * tf + fr][ke * 32 + fq * 8];
            acc[tf] = __builtin_amdgcn_mfma_f32_16x16x32_bf16(af, bfv, acc[tf], 0, 0, 0);
        }
    }
#pragma unroll
    for (int tf = 0; tf < 8; ++tf)
#pragma unroll
        for (int r = 0; r < 4; ++r) {
            int t = 16 * w + fq * 4 + r;
            qb[tok0 + (size_t)t * 2048 + 16 * tf + fr] = f2us(acc[tf][r]);
        }
}

// =============== RMSNorm (in-place, bf16) ===============
__global__ __launch_bounds__(256) void rmsnorm_kernel(unsigned short* __restrict__ o,
                                                      const float* __restrict__ w)
{
    __shared__ float red[4];
    const int row = blockIdx.x;
    const int tid = threadIdx.x;
    unsigned short* p = o + (size_t)row * 2048 + tid * 8;
    __align__(16) unsigned short u[8];
    *(uint4*)u = *(const uint4*)p;
    float f[8];
    float ss = 0.f;
#pragma unroll
    for (int j = 0; j < 8; ++j) { f[j] = us2f(u[j]); ss = fmaf(f[j], f[j], ss); }
#pragma unroll
    for (int off = 32; off > 0; off >>= 1) ss += __shfl_down(ss, off, 64);
    if ((tid & 63) == 0) red[tid >> 6] = ss;
    __syncthreads();
    float tot = red[0] + red[1] + red[2] + red[3];
    float scale = rsqrtf(tot * (1.f / 2048.f) + 1e-6f);
    const float* wp = w + tid * 8;
#pragma unroll
    for (int j = 0; j < 8; ++j) u[j] = f2us(f[j] * scale * wp[j]);
    *(uint4*)p = *(const uint4*)u;
}

extern "C" void kernel_launch(void* const* d_in, const int* in_sizes, int n_in,
                              void* d_out, int out_size, void* d_ws, size_t ws_size,
                              hipStream_t stream)
{
    const float* x  = (const float*)d_in[0];
    const float* Wq = (const float*)d_in[1];
    const float* Wk = (const float*)d_in[2];
    const float* Wv = (const float*)d_in[3];
    const float* Wo = (const float*)d_in[4];
    const float* nw = (const float*)d_in[5];
    float* out = (float*)d_out;

    const int M = 16384, N = 2048, K = 2048;
    const size_t S1 = (size_t)M * N;
    const size_t SW = (size_t)N * K;
    const size_t UTsz = (size_t)4096 * 16384;

    unsigned short* xb  = (unsigned short*)d_ws;
    unsigned short* Wqb = xb + S1;
    unsigned short* Wkb = Wqb + SW;
    unsigned short* Wvb = Wkb + SW;
    unsigned short* Wob = Wvb + SW;
    unsigned short* qb  = Wob + SW;   // q -> qdec -> o
    unsigned short* vbf = qb + S1;
    unsigned short* lfb = vbf + S1;   // log_f -> kdec
    unsigned short* obf = lfb + S1;   // intra frags
    unsigned short* UT  = obf + S1;   // U^T then S^T (in-place scan)
    float* dbuf = (float*)(UT + UTsz);

    cast_bf16<<<(int)(S1 / 8 / 256), 256, 0, stream>>>(x, xb, (int)(S1 / 8));
    cast_bf16<<<(int)(SW / 8 / 256), 256, 0, stream>>>(Wq, Wqb, (int)(SW / 8));
    cast_bf16<<<(int)(SW / 8 / 256), 256, 0, stream>>>(Wk, Wkb, (int)(SW / 8));
    cast_bf16<<<(int)(SW / 8 / 256), 256, 0, stream>>>(Wv, Wvb, (int)(SW / 8));
    cast_bf16<<<(int)(SW / 8 / 256), 256, 0, stream>>>(Wo, Wob, (int)(SW / 8));

    dim3 gg(M / 256, N / 256);  // x fastest => same-n0 tiles consecutive; A-panel reuse same-XCD (64%8==0)
    gemm_bt_mfma<EPI_SILU,  true><<<gg, 512, 0, stream>>>(xb, Wqb, qb,  M, N, K);
    gemm_bt_mfma<EPI_LOGSIG,true><<<gg, 512, 0, stream>>>(xb, Wkb, lfb, M, N, K);
    gemm_bt_mfma<EPI_NONE,  true><<<gg, 512, 0, stream>>>(xb, Wvb, vbf, M, N, K);

    gla_a1<<<4096, 256, 0, stream>>>(qb, lfb, vbf, obf, dbuf);
    gla_a2<<<4096, 256, 0, stream>>>(lfb, vbf, dbuf, UT);
    gla_scan<<<512, 256, 0, stream>>>(UT, dbuf);
    gla_c<<<4096, 256, 0, stream>>>(qb, UT, obf);

    rmsnorm_kernel<<<16384, 256, 0, stream>>>(qb, nw);
    gemm_bt_mfma<EPI_NONE, false><<<gg, 512, 0, stream>>>(qb, Wob, out, M, N, K);
}

// Round 2
// 1287.817 us; speedup vs baseline: 1.0535x; 1.0006x over previous
//
#include <hip/hip_runtime.h>
#include <cstdint>
#include <cstddef>

#define EPI_NONE 0
#define EPI_SILU 1
#define EPI_LOGSIG 2

typedef __attribute__((ext_vector_type(8))) short bf16x8;
typedef __attribute__((ext_vector_type(4))) float f32x4;

// ---- bf16 helpers on raw ushort ----
__device__ __forceinline__ float us2f(unsigned short u) {
    unsigned int x = ((unsigned int)u) << 16;
    return __uint_as_float(x);
}
__device__ __forceinline__ unsigned short f2us(float f) {
    unsigned int x = __float_as_uint(f);
    unsigned int r = (x + 0x7fffu + ((x >> 16) & 1u)) >> 16;
    return (unsigned short)r;
}

// async global->LDS, 16 bytes per lane; LDS dest = wave-uniform base + lane*16
__device__ __forceinline__ void gl_lds16(const unsigned short* g, unsigned short* l) {
    __builtin_amdgcn_global_load_lds(
        (const __attribute__((address_space(1))) void*)g,
        (__attribute__((address_space(3))) void*)l, 16, 0, 0);
}

// raw barrier (no implicit vmcnt/lgkm drain, unlike __syncthreads)
#define BARR() asm volatile("s_barrier" ::: "memory")
#define LGKM0() do { asm volatile("s_waitcnt lgkmcnt(0)" ::: "memory"); \
                     __builtin_amdgcn_sched_barrier(0); } while (0)
#define VMCNT(n) do { asm volatile("s_waitcnt vmcnt(" #n ")" ::: "memory"); \
                      __builtin_amdgcn_sched_barrier(0); } while (0)

template<int EPI>
__device__ __forceinline__ float act(float z) {
    if constexpr (EPI == EPI_SILU) {
        return z / (1.f + __expf(-z));
    } else if constexpr (EPI == EPI_LOGSIG) {
        float s = 1.f / (1.f + __expf(-z));
        return -log1pf(__expf(-s));
    }
    return z;
}

// =============== cast fp32 -> bf16, 8 elems/thread ===============
__global__ __launch_bounds__(256) void cast_bf16(const float* __restrict__ in,
                                                 unsigned short* __restrict__ out, int n8)
{
    int i = blockIdx.x * blockDim.x + threadIdx.x;
    if (i >= n8) return;
    const float4* p = (const float4*)(in + (size_t)i * 8);
    float4 a = p[0], b = p[1];
    __align__(16) unsigned short u[8];
    u[0] = f2us(a.x); u[1] = f2us(a.y); u[2] = f2us(a.z); u[3] = f2us(a.w);
    u[4] = f2us(b.x); u[5] = f2us(b.y); u[6] = f2us(b.z); u[7] = f2us(b.w);
    *(uint4*)(out + (size_t)i * 8) = *(const uint4*)u;
}

// ---- fragment loads from XOR-swizzled [256][64] LDS tile ----
__device__ __forceinline__ void ld_a4(bf16x8 d[4][2], const unsigned short* buf,
                                      int rowbase, int fr, int fq, int rx)
{
#pragma unroll
    for (int t = 0; t < 4; ++t) {
        const int row = rowbase + t * 16 + fr;
#pragma unroll
        for (int ks = 0; ks < 2; ++ks)
            d[t][ks] = *(const bf16x8*)&buf[row * 64 + ((((ks << 2) + fq) ^ rx) << 3)];
    }
}
__device__ __forceinline__ void ld_b2(bf16x8 d[2][2], const unsigned short* buf,
                                      int rowbase, int fr, int fq, int rx)
{
#pragma unroll
    for (int t = 0; t < 2; ++t) {
        const int row = rowbase + t * 16 + fr;
#pragma unroll
        for (int ks = 0; ks < 2; ++ks)
            d[t][ks] = *(const bf16x8*)&buf[row * 64 + ((((ks << 2) + fq) ^ rx) << 3)];
    }
}
__device__ __forceinline__ void mma_q(f32x4 acc[8][4], const bf16x8 a[4][2], const bf16x8 b[2][2],
                                      int ti0, int tj0)
{
#pragma unroll
    for (int ks = 0; ks < 2; ++ks)
#pragma unroll
        for (int i = 0; i < 4; ++i)
#pragma unroll
            for (int j = 0; j < 2; ++j)
                acc[ti0 + i][tj0 + j] = __builtin_amdgcn_mfma_f32_16x16x32_bf16(
                    a[i][ks], b[j][ks], acc[ti0 + i][tj0 + j], 0, 0, 0);
}

// =============== bf16 MFMA GEMM v3.1: 256x256 tile, BK=64, 8-phase counted-vmcnt ===============
// C[M,N] = act(A[M,K] * B[N,K]^T). 512 threads = 8 waves (2M x 4N), per-wave 128x64 out.
// LDS 128 KiB: double-buffered A/B K-tiles, XOR-swizzled (conflict-free ds_read_b128).
// __launch_bounds__(512, 1): 256-VGPR budget -- acc[8][4]=128 VGPR must NOT spill
// (round-1 lesson: (512,2) capped at 128 VGPR -> acc spilled to scratch, WRITE_SIZE 5x).
// Schedule (per K-tile T, 4 phases; vmcnt never drained to 0 in steady state):
//   ph1: ds A-lo(8)+B-lo(4) | stage (T+1,A1) | bar | lgkm0 | 16 mfma q0 | bar
//   ph2: ds B-hi(4)         |                | bar | lgkm0 | 16 mfma q1 | bar
//   ph3: ds A-hi(8)         | stage (T+2,B0) | bar | lgkm0 | 16 mfma q2 | bar
//   ph4:                    | stage (T+2,B1),(T+2,A0) | vmcnt(6) | bar | lgkm0 | 16 mfma q3 | bar
// Race-safety: all B rows of the live buffer are dead after ph2; A rows {wr..wr+63} after
// ph1, {wr+64..wr+127} after ph3 => T+2 stages (same buffer as T) only touch dead regions.
// vmcnt(6) tail = the 3 T+2 halves => all of T+1 resident before its ph1 reads.
template<int EPI, bool OUT_BF16>
__global__ __launch_bounds__(512, 1) void gemm_bt_mfma(const unsigned short* __restrict__ A,
                                                       const unsigned short* __restrict__ B,
                                                       void* __restrict__ Cv,
                                                       int M, int N, int K)
{
    __shared__ unsigned short smem[65536];        // 128 KB: [As0|Bs0|As1|Bs1] x 16384 elems

    const int tid  = threadIdx.x;
    const int lane = tid & 63;
    const int wv   = tid >> 6;                    // 0..7
    const int m0   = blockIdx.x * 256;
    const int n0   = blockIdx.y * 256;
    const int wr   = (wv >> 2) * 128;             // 0 | 128
    const int wc   = (wv & 3) * 64;               // 0 | 64 | 128 | 192
    const int fr   = lane & 15;
    const int fq   = lane >> 4;
    const int rx   = fr & 7;
    const int NT   = K >> 6;

    unsigned short* const As0 = smem;
    unsigned short* const Bs0 = smem + 16384;
    unsigned short* const As1 = smem + 32768;
    unsigned short* const Bs1 = smem + 49152;

    // staging: per half-tile (128 rows x 64 cols) 2 instrs; wave w owns rows w*8..w*8+7 of
    // each 64-row instr-block. lane l: row-in-group l>>3, source k-chunk (l&7)^(l>>3)
    // (pre-swizzled global source, linear LDS dest -> swizzled tile).
    const int srow = wv * 8 + (lane >> 3);
    const int scol = ((lane & 7) ^ (lane >> 3)) << 3;
    const unsigned short* Ag[2][2];
    const unsigned short* Bg[2][2];
#pragma unroll
    for (int h = 0; h < 2; ++h)
#pragma unroll
        for (int i = 0; i < 2; ++i) {
            Ag[h][i] = A + (size_t)(m0 + h * 128 + i * 64 + srow) * K + scol;
            Bg[h][i] = B + (size_t)(n0 + h * 128 + i * 64 + srow) * K + scol;
        }

#define STAGE(gb, lb, h, Tt) do {                                         \
        unsigned short* _l = (lb) + (h) * 8192 + wv * 512;                \
        gl_lds16(gb[h][0] + (size_t)(Tt) * 64, _l);                       \
        gl_lds16(gb[h][1] + (size_t)(Tt) * 64, _l + 4096);                \
    } while (0)

    f32x4 acc[8][4];
#pragma unroll
    for (int i = 0; i < 8; ++i)
#pragma unroll
        for (int j = 0; j < 4; ++j) acc[i][j] = (f32x4){0.f, 0.f, 0.f, 0.f};

    bf16x8 af[4][2], b0[2][2], b1[2][2];

    // ---- prologue: tile0 full + tile1 {B0,B1,A0}; A1 of tile1 is staged in T=0 ph1 ----
    STAGE(Ag, As0, 0, 0); STAGE(Ag, As0, 1, 0);
    STAGE(Bg, Bs0, 0, 0); STAGE(Bg, Bs0, 1, 0);
    STAGE(Bg, Bs1, 0, 1); STAGE(Bg, Bs1, 1, 1);
    STAGE(Ag, As1, 0, 1);
    VMCNT(6);                                     // tile0 resident; 3 halves in flight
    BARR();

    for (int T = 0; T < NT; ++T) {
        const int pb = T & 1;
        unsigned short* const Ab  = smem + pb * 32768;
        unsigned short* const Bb  = Ab + 16384;
        unsigned short* const Anx = smem + (pb ^ 1) * 32768;

        // ---- phase 1: q0 = A-lo x B-lo ----
        ld_a4(af, Ab, wr, fr, fq, rx);
        ld_b2(b0, Bb, wc, fr, fq, rx);
        if (T + 1 < NT) STAGE(Ag, Anx, 1, T + 1);
        BARR(); LGKM0();
        __builtin_amdgcn_s_setprio(1);
        mma_q(acc, af, b0, 0, 0);
        __builtin_amdgcn_s_setprio(0);
        BARR();

        // ---- phase 2: q1 = A-lo x B-hi ----
        ld_b2(b1, Bb, wc + 32, fr, fq, rx);
        BARR(); LGKM0();
        __builtin_amdgcn_s_setprio(1);
        mma_q(acc, af, b1, 0, 2);
        __builtin_amdgcn_s_setprio(0);
        BARR();

        // ---- phase 3: q2 = A-hi x B-lo ----
        ld_a4(af, Ab, wr + 64, fr, fq, rx);
        if (T + 2 < NT) STAGE(Bg, Bb, 0, T + 2);   // whole B dead since ph2-end
        BARR(); LGKM0();
        __builtin_amdgcn_s_setprio(1);
        mma_q(acc, af, b0, 4, 0);
        __builtin_amdgcn_s_setprio(0);
        BARR();

        // ---- phase 4: q3 = A-hi x B-hi ----
        if (T + 2 < NT) { STAGE(Bg, Bb, 1, T + 2); STAGE(Ag, Ab, 0, T + 2); }
        if (T + 2 < NT)      { VMCNT(6); }         // forces all of tile T+1 resident
        else if (T + 1 < NT) { VMCNT(0); }         // last prefetched tile: full drain
        BARR(); LGKM0();
        __builtin_amdgcn_s_setprio(1);
        mma_q(acc, af, b1, 4, 2);
        __builtin_amdgcn_s_setprio(0);
        BARR();
    }
#undef STAGE

    // C/D layout: col = lane&15, row = (lane>>4)*4 + reg
    const int crow = fq * 4;
    const int ccol = fr;

    if (OUT_BF16) {
        VMCNT(0);                                  // nothing should be in flight; belt+braces
        unsigned short* Cs = smem;                 // [128][264] per half
        // ---- half 0 (rows m0..m0+127): waves wr==0 hold all of it ----
        if (wr == 0) {
#pragma unroll
            for (int ti = 0; ti < 8; ++ti)
#pragma unroll
                for (int r = 0; r < 4; ++r)
#pragma unroll
                    for (int tj = 0; tj < 4; ++tj)
                        Cs[(ti * 16 + crow + r) * 264 + wc + tj * 16 + ccol] =
                            f2us(act<EPI>(acc[ti][tj][r]));
        }
        LGKM0(); BARR();
        {
            const int row = tid >> 2, cb = (tid & 3) << 6;
            const unsigned short* src = &Cs[row * 264 + cb];
            unsigned short* dst = (unsigned short*)Cv + (size_t)(m0 + row) * N + n0 + cb;
#pragma unroll
            for (int j = 0; j < 8; ++j)
                *(uint4*)(dst + j * 8) = *(const uint4*)(src + j * 8);
        }
        BARR();
        // ---- half 1 (rows m0+128..m0+255): waves wr==128 ----
        if (wr == 128) {
#pragma unroll
            for (int ti = 0; ti < 8; ++ti)
#pragma unroll
                for (int r = 0; r < 4; ++r)
#pragma unroll
                    for (int tj = 0; tj < 4; ++tj)
                        Cs[(ti * 16 + crow + r) * 264 + wc + tj * 16 + ccol] =
                            f2us(act<EPI>(acc[ti][tj][r]));
        }
        LGKM0(); BARR();
        {
            const int row = tid >> 2, cb = (tid & 3) << 6;
            const unsigned short* src = &Cs[row * 264 + cb];
            unsigned short* dst = (unsigned short*)Cv + (size_t)(m0 + 128 + row) * N + n0 + cb;
#pragma unroll
            for (int j = 0; j < 8; ++j)
                *(uint4*)(dst + j * 8) = *(const uint4*)(src + j * 8);
        }
    } else {
        float* C = (float*)Cv;
#pragma unroll
        for (int ti = 0; ti < 8; ++ti)
#pragma unroll
            for (int r = 0; r < 4; ++r) {
                const int row = m0 + wr + ti * 16 + crow + r;
#pragma unroll
                for (int tj = 0; tj < 4; ++tj)
                    C[(size_t)row * N + n0 + wc + tj * 16 + ccol] = act<EPI>(acc[ti][tj][r]);
            }
    }
}

// =============== GLA pass A1: decays + scores + intra (per chunk,bh) ===============
__global__ __launch_bounds__(256) void gla_a1(unsigned short* __restrict__ qb,
                                              unsigned short* __restrict__ lfb,
                                              const unsigned short* __restrict__ vb,
                                              unsigned short* __restrict__ obf,
                                              float* __restrict__ dbuf)
{
    __shared__ unsigned short q_sh[64][136];
    __shared__ unsigned short kd_sh[64][136];
    __shared__ unsigned short vT[128][72];   // v^T [f][t]
    __shared__ unsigned short sc[64][72];    // scores [t][s]

    const int tid = threadIdx.x;
    const int bid = blockIdx.x;
    const int c = bid >> 6, bh = bid & 63;
    const int b = bh >> 4, h = bh & 15;
    const size_t tok0 = ((size_t)b * 4096 + (size_t)c * 64) * 2048 + (size_t)h * 128;

#pragma unroll
    for (int k = 0; k < 4; ++k) {
        int vi = tid + k * 256;
        int t = vi >> 4, e8 = (vi & 15) << 3;
        *(uint4*)&q_sh[t][e8]  = *(const uint4*)(qb  + tok0 + (size_t)t * 2048 + e8);
        *(uint4*)&kd_sh[t][e8] = *(const uint4*)(lfb + tok0 + (size_t)t * 2048 + e8);
    }
    if (tid < 128) {
        int t8 = tid >> 4, f8 = tid & 15;
        __align__(16) unsigned short a[8][8];
#pragma unroll
        for (int r = 0; r < 8; ++r)
            *(uint4*)a[r] = *(const uint4*)(vb + tok0 + (size_t)(t8 * 8 + r) * 2048 + f8 * 8);
#pragma unroll
        for (int j = 0; j < 8; ++j) {
            __align__(16) unsigned short w8[8];
#pragma unroll
            for (int r = 0; r < 8; ++r) w8[r] = a[r][j];
            *(uint4*)&vT[f8 * 8 + j][t8 * 8] = *(const uint4*)w8;
        }
    }
    __syncthreads();
    if (tid < 128) {
        const int e = tid;
        float a = 0.f;
        for (int t = 0; t < 64; ++t) {
            float lf = us2f(kd_sh[t][e]);
            a += lf;
            q_sh[t][e]  = f2us(us2f(q_sh[t][e]) * __expf(a));       // q_dec
            kd_sh[t][e] = f2us((1.f - __expf(lf)) * __expf(-a));    // k_dec
        }
        dbuf[(size_t)bid * 128 + e] = __expf(a);
    }
    __syncthreads();
#pragma unroll
    for (int k = 0; k < 4; ++k) {
        int vi = tid + k * 256;
        int t = vi >> 4, e8 = (vi & 15) << 3;
        *(uint4*)(qb  + tok0 + (size_t)t * 2048 + e8) = *(const uint4*)&q_sh[t][e8];
        *(uint4*)(lfb + tok0 + (size_t)t * 2048 + e8) = *(const uint4*)&kd_sh[t][e8];
    }

    const int lane = tid & 63, w = tid >> 6;
    const int fr = lane & 15, fq = lane >> 4;

    // scores = qdec @ kdec^T
    f32x4 sacc[4];
#pragma unroll
    for (int j = 0; j < 4; ++j) sacc[j] = (f32x4){0.f, 0.f, 0.f, 0.f};
#pragma unroll
    for (int ke = 0; ke < 4; ++ke) {
        bf16x8 af = *(const bf16x8*)&q_sh[16 * w + fr][ke * 32 + fq * 8];
#pragma unroll
        for (int tj = 0; tj < 4; ++tj) {
            bf16x8 bfv = *(const bf16x8*)&kd_sh[16 * tj + fr][ke * 32 + fq * 8];
            sacc[tj] = __builtin_amdgcn_mfma_f32_16x16x32_bf16(af, bfv, sacc[tj], 0, 0, 0);
        }
    }
#pragma unroll
    for (int tj = 0; tj < 4; ++tj)
#pragma unroll
        for (int r = 0; r < 4; ++r) {
            int trow = 16 * w + fq * 4 + r;
            int scol = 16 * tj + fr;
            sc[trow][scol] = f2us(scol <= trow ? sacc[tj][r] : 0.f);
        }
    __syncthreads();
    // intra = sc @ v
    f32x4 oacc[8];
#pragma unroll
    for (int j = 0; j < 8; ++j) oacc[j] = (f32x4){0.f, 0.f, 0.f, 0.f};
#pragma unroll
    for (int ks = 0; ks < 2; ++ks) {
        bf16x8 af = *(const bf16x8*)&sc[16 * w + fr][ks * 32 + fq * 8];
#pragma unroll
        for (int tf = 0; tf < 8; ++tf) {
            bf16x8 bfv = *(const bf16x8*)&vT[16 * tf + fr][ks * 32 + fq * 8];
            oacc[tf] = __builtin_amdgcn_mfma_f32_16x16x32_bf16(af, bfv, oacc[tf], 0, 0, 0);
        }
    }
#pragma unroll
    for (int tf = 0; tf < 8; ++tf) {
        __align__(8) unsigned short o4[4];
#pragma unroll
        for (int r = 0; r < 4; ++r) o4[r] = f2us(oacc[tf][r]);
        *(uint2*)(obf + (((size_t)bid * 4 + w) * 8 + tf) * 256 + lane * 4) = *(const uint2*)o4;
    }
}

// =============== GLA pass A2: U^T[f][e] = d[e] * sum_t kdec[t][e] v[t][f] ===============
__global__ __launch_bounds__(256) void gla_a2(const unsigned short* __restrict__ lfb, // kdec
                                              const unsigned short* __restrict__ vb,
                                              const float* __restrict__ dbuf,
                                              unsigned short* __restrict__ UT)
{
    __shared__ unsigned short vT[128][72];
    __shared__ unsigned short kdT[128][72];
    __shared__ float d_sh[128];

    const int tid = threadIdx.x;
    const int bid = blockIdx.x;
    const int c = bid >> 6, bh = bid & 63;
    const int b = bh >> 4, h = bh & 15;
    const size_t tok0 = ((size_t)b * 4096 + (size_t)c * 64) * 2048 + (size_t)h * 128;

    if (tid < 128) {
        int t8 = tid >> 4, f8 = tid & 15;
        __align__(16) unsigned short a[8][8];
#pragma unroll
        for (int r = 0; r < 8; ++r)
            *(uint4*)a[r] = *(const uint4*)(vb + tok0 + (size_t)(t8 * 8 + r) * 2048 + f8 * 8);
#pragma unroll
        for (int j = 0; j < 8; ++j) {
            __align__(16) unsigned short w8[8];
#pragma unroll
            for (int r = 0; r < 8; ++r) w8[r] = a[r][j];
            *(uint4*)&vT[f8 * 8 + j][t8 * 8] = *(const uint4*)w8;
        }
        d_sh[tid] = dbuf[(size_t)bid * 128 + tid];
    } else {
        int i = tid - 128;
        int t8 = i >> 4, e8b = i & 15;
        __align__(16) unsigned short a[8][8];
#pragma unroll
        for (int r = 0; r < 8; ++r)
            *(uint4*)a[r] = *(const uint4*)(lfb + tok0 + (size_t)(t8 * 8 + r) * 2048 + e8b * 8);
#pragma unroll
        for (int j = 0; j < 8; ++j) {
            __align__(16) unsigned short w8[8];
#pragma unroll
            for (int r = 0; r < 8; ++r) w8[r] = a[r][j];
            *(uint4*)&kdT[e8b * 8 + j][t8 * 8] = *(const uint4*)w8;
        }
    }
    __syncthreads();

    const int lane = tid & 63, w = tid >> 6;
    const int fr = lane & 15, fq = lane >> 4;

    f32x4 acc[2][8];
#pragma unroll
    for (int mi = 0; mi < 2; ++mi)
#pragma unroll
        for (int te = 0; te < 8; ++te) acc[mi][te] = (f32x4){0.f, 0.f, 0.f, 0.f};
#pragma unroll
    for (int kt = 0; kt < 2; ++kt) {
        bf16x8 af0 = *(const bf16x8*)&vT[16 * (2 * w + 0) + fr][kt * 32 + fq * 8];
        bf16x8 af1 = *(const bf16x8*)&vT[16 * (2 * w + 1) + fr][kt * 32 + fq * 8];
#pragma unroll
        for (int te = 0; te < 8; ++te) {
            bf16x8 bfv = *(const bf16x8*)&kdT[16 * te + fr][kt * 32 + fq * 8];
            acc[0][te] = __builtin_amdgcn_mfma_f32_16x16x32_bf16(af0, bfv, acc[0][te], 0, 0, 0);
            acc[1][te] = __builtin_amdgcn_mfma_f32_16x16x32_bf16(af1, bfv, acc[1][te], 0, 0, 0);
        }
    }
    unsigned short* up = UT + (size_t)bid * 16384;
#pragma unroll
    for (int mi = 0; mi < 2; ++mi)
#pragma unroll
        for (int te = 0; te < 8; ++te) {
            int e = 16 * te + fr;
            float dv = d_sh[e];
#pragma unroll
            for (int r = 0; r < 4; ++r) {
                int f = 32 * w + 16 * mi + fq * 4 + r;
                up[f * 128 + e] = f2us(acc[mi][te][r] * dv);
            }
        }
}

// =============== GLA pass B: in-place scan UT[c] -> S-before-chunk-c ===============
__global__ __launch_bounds__(256) void gla_scan(unsigned short* __restrict__ UT,
                                                const float* __restrict__ dbuf)
{
    const int tid = threadIdx.x;
    const int bh = blockIdx.x >> 3, fs = blockIdx.x & 7;
    const int f = fs * 16 + (tid >> 4);
    const int e8 = (tid & 15) << 3;
    float S[8];
#pragma unroll
    for (int j = 0; j < 8; ++j) S[j] = 0.f;
    for (int c = 0; c < 64; ++c) {
        const size_t cb = (size_t)(c * 64 + bh);
        const size_t loc = cb * 16384 + (size_t)f * 128 + e8;
        uint4 uu = *(const uint4*)(UT + loc);
        float4 d0 = *(const float4*)(dbuf + cb * 128 + e8);
        float4 d1 = *(const float4*)(dbuf + cb * 128 + e8 + 4);
        __align__(16) unsigned short us8[8];
        *(uint4*)us8 = uu;
        __align__(16) unsigned short so[8];
#pragma unroll
        for (int j = 0; j < 8; ++j) so[j] = f2us(S[j]);
        *(uint4*)(UT + loc) = *(const uint4*)so;
        float dd[8] = {d0.x, d0.y, d0.z, d0.w, d1.x, d1.y, d1.z, d1.w};
#pragma unroll
        for (int j = 0; j < 8; ++j) S[j] = fmaf(dd[j], S[j], us2f(us8[j]));
    }
}

// =============== GLA pass C: o = intra + qdec @ S^T; write o over qb ===============
__global__ __launch_bounds__(256) void gla_c(unsigned short* __restrict__ qb,
                                             const unsigned short* __restrict__ UT, // = S^T[f][e]
                                             const unsigned short* __restrict__ obf)
{
    __shared__ unsigned short q_sh[64][136];
    __shared__ unsigned short ST_sh[128][136];

    const int tid = threadIdx.x;
    const int bid = blockIdx.x;
    const int c = bid >> 6, bh = bid & 63;
    const int b = bh >> 4, h = bh & 15;
    const size_t tok0 = ((size_t)b * 4096 + (size_t)c * 64) * 2048 + (size_t)h * 128;

#pragma unroll
    for (int k = 0; k < 4; ++k) {
        int vi = tid + k * 256;
        int t = vi >> 4, e8 = (vi & 15) << 3;
        *(uint4*)&q_sh[t][e8] = *(const uint4*)(qb + tok0 + (size_t)t * 2048 + e8);
    }
    const unsigned short* stp = UT + (size_t)bid * 16384;
#pragma unroll
    for (int k = 0; k < 8; ++k) {
        int vi = tid + k * 256;
        int f = vi >> 4, e8 = (vi & 15) << 3;
        *(uint4*)&ST_sh[f][e8] = *(const uint4*)(stp + (size_t)f * 128 + e8);
    }
    const int lane = tid & 63, w = tid >> 6;
    const int fr = lane & 15, fq = lane >> 4;

    f32x4 acc[8];
#pragma unroll
    for (int tf = 0; tf < 8; ++tf) {
        uint2 iv = *(const uint2*)(obf + (((size_t)bid * 4 + w) * 8 + tf) * 256 + lane * 4);
        __align__(8) unsigned short s4[4];
        *(uint2*)s4 = iv;
        acc[tf] = (f32x4){us2f(s4[0]), us2f(s4[1]), us2f(s4[2]), us2f(s4[3])};
    }
    __syncthreads();
#pragma unroll
    for (int ke = 0; ke < 4; ++ke) {
        bf16x8 af = *(const bf16x8*)&q_sh[16 * w + fr][ke * 32 + fq * 8];
#pragma unroll
        for (int tf = 0; tf < 8; ++tf) {
            bf16x8 bfv = *(const bf16x8*)&ST_sh[16 * tf + fr][ke * 32 + fq * 8];
            acc[tf] = __builtin_amdgcn_mfma_f32_16x16x32_bf16(af, bfv, acc[tf], 0, 0, 0);
        }
    }
#pragma unroll
    for (int tf = 0; tf < 8; ++tf)
#pragma unroll
        for (int r = 0; r < 4; ++r) {
            int t = 16 * w + fq * 4 + r;
            qb[tok0 + (size_t)t * 2048 + 16 * tf + fr] = f2us(acc[tf][r]);
        }
}

// =============== RMSNorm (in-place, bf16) ===============
__global__ __launch_bounds__(256) void rmsnorm_kernel(unsigned short* __restrict__ o,
                                                      const float* __restrict__ w)
{
    __shared__ float red[4];
    const int row = blockIdx.x;
    const int tid = threadIdx.x;
    unsigned short* p = o + (size_t)row * 2048 + tid * 8;
    __align__(16) unsigned short u[8];
    *(uint4*)u = *(const uint4*)p;
    float f[8];
    float ss = 0.f;
#pragma unroll
    for (int j = 0; j < 8; ++j) { f[j] = us2f(u[j]); ss = fmaf(f[j], f[j], ss); }
#pragma unroll
    for (int off = 32; off > 0; off >>= 1) ss += __shfl_down(ss, off, 64);
    if ((tid & 63) == 0) red[tid >> 6] = ss;
    __syncthreads();
    float tot = red[0] + red[1] + red[2] + red[3];
    float scale = rsqrtf(tot * (1.f / 2048.f) + 1e-6f);
    const float* wp = w + tid * 8;
#pragma unroll
    for (int j = 0; j < 8; ++j) u[j] = f2us(f[j] * scale * wp[j]);
    *(uint4*)p = *(const uint4*)u;
}

extern "C" void kernel_launch(void* const* d_in, const int* in_sizes, int n_in,
                              void* d_out, int out_size, void* d_ws, size_t ws_size,
                              hipStream_t stream)
{
    const float* x  = (const float*)d_in[0];
    const float* Wq = (const float*)d_in[1];
    const float* Wk = (const float*)d_in[2];
    const float* Wv = (const float*)d_in[3];
    const float* Wo = (const float*)d_in[4];
    const float* nw = (const float*)d_in[5];
    float* out = (float*)d_out;

    const int M = 16384, N = 2048, K = 2048;
    const size_t S1 = (size_t)M * N;
    const size_t SW = (size_t)N * K;
    const size_t UTsz = (size_t)4096 * 16384;

    unsigned short* xb  = (unsigned short*)d_ws;
    unsigned short* Wqb = xb + S1;
    unsigned short* Wkb = Wqb + SW;
    unsigned short* Wvb = Wkb + SW;
    unsigned short* Wob = Wvb + SW;
    unsigned short* qb  = Wob + SW;   // q -> qdec -> o
    unsigned short* vbf = qb + S1;
    unsigned short* lfb = vbf + S1;   // log_f -> kdec
    unsigned short* obf = lfb + S1;   // intra frags
    unsigned short* UT  = obf + S1;   // U^T then S^T (in-place scan)
    float* dbuf = (float*)(UT + UTsz);

    cast_bf16<<<(int)(S1 / 8 / 256), 256, 0, stream>>>(x, xb, (int)(S1 / 8));
    cast_bf16<<<(int)(SW / 8 / 256), 256, 0, stream>>>(Wq, Wqb, (int)(SW / 8));
    cast_bf16<<<(int)(SW / 8 / 256), 256, 0, stream>>>(Wk, Wkb, (int)(SW / 8));
    cast_bf16<<<(int)(SW / 8 / 256), 256, 0, stream>>>(Wv, Wvb, (int)(SW / 8));
    cast_bf16<<<(int)(SW / 8 / 256), 256, 0, stream>>>(Wo, Wob, (int)(SW / 8));

    dim3 gg(M / 256, N / 256);  // x fastest => same-n0 tiles consecutive; A-panel reuse same-XCD (64%8==0)
    gemm_bt_mfma<EPI_SILU,  true><<<gg, 512, 0, stream>>>(xb, Wqb, qb,  M, N, K);
    gemm_bt_mfma<EPI_LOGSIG,true><<<gg, 512, 0, stream>>>(xb, Wkb, lfb, M, N, K);
    gemm_bt_mfma<EPI_NONE,  true><<<gg, 512, 0, stream>>>(xb, Wvb, vbf, M, N, K);

    gla_a1<<<4096, 256, 0, stream>>>(qb, lfb, vbf, obf, dbuf);
    gla_a2<<<4096, 256, 0, stream>>>(lfb, vbf, dbuf, UT);
    gla_scan<<<512, 256, 0, stream>>>(UT, dbuf);
    gla_c<<<4096, 256, 0, stream>>>(qb, UT, obf);

    rmsnorm_kernel<<<16384, 256, 0, stream>>>(qb, nw);
    gemm_bt_mfma<EPI_NONE, false><<<gg, 512, 0, stream>>>(qb, Wob, out, M, N, K);
}

// Round 3
// 1232.340 us; speedup vs baseline: 1.1009x; 1.0450x over previous
//
#include <hip/hip_runtime.h>
#include <cstdint>
#include <cstddef>

#define EPI_NONE 0
#define EPI_SILU 1
#define EPI_LOGSIG 2

typedef __attribute__((ext_vector_type(8))) short bf16x8;
typedef __attribute__((ext_vector_type(4))) float f32x4;

// ---- bf16 helpers on raw ushort ----
__device__ __forceinline__ float us2f(unsigned short u) {
    unsigned int x = ((unsigned int)u) << 16;
    return __uint_as_float(x);
}
__device__ __forceinline__ unsigned short f2us(float f) {
    unsigned int x = __float_as_uint(f);
    unsigned int r = (x + 0x7fffu + ((x >> 16) & 1u)) >> 16;
    return (unsigned short)r;
}

// async global->LDS, 16 bytes per lane; LDS dest = wave-uniform base + lane*16
__device__ __forceinline__ void gl_lds16(const unsigned short* g, unsigned short* l) {
    __builtin_amdgcn_global_load_lds(
        (const __attribute__((address_space(1))) void*)g,
        (__attribute__((address_space(3))) void*)l, 16, 0, 0);
}

// raw barrier (no implicit vmcnt/lgkm drain, unlike __syncthreads)
#define BARR() asm volatile("s_barrier" ::: "memory")
#define LGKM0() do { asm volatile("s_waitcnt lgkmcnt(0)" ::: "memory"); \
                     __builtin_amdgcn_sched_barrier(0); } while (0)
#define VMCNT(n) do { asm volatile("s_waitcnt vmcnt(" #n ")" ::: "memory"); \
                      __builtin_amdgcn_sched_barrier(0); } while (0)

template<int EPI>
__device__ __forceinline__ float act(float z) {
    if constexpr (EPI == EPI_SILU) {
        return z / (1.f + __expf(-z));
    } else if constexpr (EPI == EPI_LOGSIG) {
        float s = 1.f / (1.f + __expf(-z));
        return -log1pf(__expf(-s));
    }
    return z;
}

// =============== cast fp32 -> bf16, 8 elems/thread ===============
__global__ __launch_bounds__(256) void cast_bf16(const float* __restrict__ in,
                                                 unsigned short* __restrict__ out, int n8)
{
    int i = blockIdx.x * blockDim.x + threadIdx.x;
    if (i >= n8) return;
    const float4* p = (const float4*)(in + (size_t)i * 8);
    float4 a = p[0], b = p[1];
    __align__(16) unsigned short u[8];
    u[0] = f2us(a.x); u[1] = f2us(a.y); u[2] = f2us(a.z); u[3] = f2us(a.w);
    u[4] = f2us(b.x); u[5] = f2us(b.y); u[6] = f2us(b.z); u[7] = f2us(b.w);
    *(uint4*)(out + (size_t)i * 8) = *(const uint4*)u;
}

// =============== bf16 MFMA GEMM v3.2: 256x256 tile, BK=64, 8-phase counted-vmcnt ===============
// C[M,N] = act(A[M,K] * B[N,K]^T). 512 threads = 8 waves (2M x 4N), per-wave 128x64 out.
// LDS 128 KiB: double-buffered A/B K-tiles, XOR-swizzled (conflict-free ds_read_b128).
//
// v3.2 LESSON (rounds 1-2): acc/frag arrays were scratch-resident (VGPR_Count=116 < 128
// needed for acc alone; +260 MB HBM write = scratch leakage; L2-bound at 357us).
// Cause: arrays passed into helper fns + runtime loop indices -- SROA runs BEFORE the
// unroll pass, sees escaped/runtime-indexed allocas, never promotes; asm "memory"
// clobbers then force real scratch traffic every phase.  Fix: EVERY register-array
// access is macro-expanded with frontend-constant indices; fragments are named scalars.
//
// Schedule (per K-tile T, 4 phases; vmcnt never drained to 0 in steady state):
//   ph1: ds A-lo(8)+B-lo(4) | stage (T+1,A1) | bar | lgkm0 | 16 mfma q0 | bar
//   ph2: ds B-hi(4)         |                | bar | lgkm0 | 16 mfma q1 | bar
//   ph3: ds A-hi(8)         | stage (T+2,B0) | bar | lgkm0 | 16 mfma q2 | bar
//   ph4:                    | stage (T+2,B1),(T+2,A0) | vmcnt(6) | bar | lgkm0 | 16 mfma q3 | bar
// Race-safety: all B rows of the live buffer are dead after ph2; A rows {wr..wr+63} after
// ph1, {wr+64..wr+127} after ph3 => T+2 stages (same buffer as T) only touch dead regions.
// vmcnt(6) tail = the 3 T+2 halves => all of T+1 resident before its ph1 reads.
template<int EPI, bool OUT_BF16>
__global__ __launch_bounds__(512, 2) void gemm_bt_mfma(const unsigned short* __restrict__ A,
                                                       const unsigned short* __restrict__ B,
                                                       void* __restrict__ Cv,
                                                       int M, int N, int K)
{
    __shared__ unsigned short smem[65536];        // 128 KB: [As0|Bs0|As1|Bs1] x 16384 elems

    const int tid  = threadIdx.x;
    const int lane = tid & 63;
    const int wv   = tid >> 6;                    // 0..7
    const int m0   = blockIdx.x * 256;
    const int n0   = blockIdx.y * 256;
    const int wr   = (wv >> 2) * 128;             // 0 | 128
    const int wc   = (wv & 3) * 64;               // 0 | 64 | 128 | 192
    const int fr   = lane & 15;
    const int fq   = lane >> 4;
    const int rx   = fr & 7;
    const int NT   = K >> 6;

    unsigned short* const As0 = smem;
    unsigned short* const Bs0 = smem + 16384;
    unsigned short* const As1 = smem + 32768;
    unsigned short* const Bs1 = smem + 49152;

    // staging: per half-tile (128 rows x 64 cols) 2 instrs; wave w owns rows w*8..w*8+7 of
    // each 64-row instr-block. lane l: row-in-group l>>3, source k-chunk (l&7)^(l>>3)
    // (pre-swizzled global source, linear LDS dest -> swizzled tile).
    const int srow = wv * 8 + (lane >> 3);
    const int scol = ((lane & 7) ^ (lane >> 3)) << 3;
    const unsigned short* const Ag00 = A + (size_t)(m0 +   0 + srow) * K + scol;
    const unsigned short* const Ag01 = A + (size_t)(m0 +  64 + srow) * K + scol;
    const unsigned short* const Ag10 = A + (size_t)(m0 + 128 + srow) * K + scol;
    const unsigned short* const Ag11 = A + (size_t)(m0 + 192 + srow) * K + scol;
    const unsigned short* const Bg00 = B + (size_t)(n0 +   0 + srow) * K + scol;
    const unsigned short* const Bg01 = B + (size_t)(n0 +  64 + srow) * K + scol;
    const unsigned short* const Bg10 = B + (size_t)(n0 + 128 + srow) * K + scol;
    const unsigned short* const Bg11 = B + (size_t)(n0 + 192 + srow) * K + scol;

#define STAGE(g0, g1, lb, hoff, Tt) do {                                  \
        unsigned short* _l = (lb) + (hoff) + wv * 512;                    \
        gl_lds16((g0) + (size_t)(Tt) * 64, _l);                           \
        gl_lds16((g1) + (size_t)(Tt) * 64, _l + 4096);                    \
    } while (0)

#define MF(a, b, c) __builtin_amdgcn_mfma_f32_16x16x32_bf16(a, b, c, 0, 0, 0)
#define KO0 (((fq) ^ rx) << 3)
#define KO1 (((4 + fq) ^ rx) << 3)

    f32x4 acc[8][4];                              // constant-index access ONLY
#define ZZ (f32x4){0.f, 0.f, 0.f, 0.f}
#define ZROW(i) acc[i][0]=ZZ; acc[i][1]=ZZ; acc[i][2]=ZZ; acc[i][3]=ZZ
    ZROW(0); ZROW(1); ZROW(2); ZROW(3); ZROW(4); ZROW(5); ZROW(6); ZROW(7);
#undef ZROW
#undef ZZ

    bf16x8 Fa00, Fa01, Fa10, Fa11, Fa20, Fa21, Fa30, Fa31;   // A half frags (t,ks)
    bf16x8 Fb00, Fb01, Fb10, Fb11;                           // B-lo frags
    bf16x8 Fc00, Fc01, Fc10, Fc11;                           // B-hi frags

#define LOAD_A_HALF(rb) do {                                              \
        const unsigned short* _p0 = &Ab[((rb) +  0 + fr) * 64];           \
        const unsigned short* _p1 = &Ab[((rb) + 16 + fr) * 64];           \
        const unsigned short* _p2 = &Ab[((rb) + 32 + fr) * 64];           \
        const unsigned short* _p3 = &Ab[((rb) + 48 + fr) * 64];           \
        Fa00 = *(const bf16x8*)(_p0 + KO0); Fa01 = *(const bf16x8*)(_p0 + KO1); \
        Fa10 = *(const bf16x8*)(_p1 + KO0); Fa11 = *(const bf16x8*)(_p1 + KO1); \
        Fa20 = *(const bf16x8*)(_p2 + KO0); Fa21 = *(const bf16x8*)(_p2 + KO1); \
        Fa30 = *(const bf16x8*)(_p3 + KO0); Fa31 = *(const bf16x8*)(_p3 + KO1); \
    } while (0)

#define LOAD_B_PAIR(d00, d01, d10, d11, rb) do {                          \
        const unsigned short* _q0 = &Bb[((rb) +  0 + fr) * 64];           \
        const unsigned short* _q1 = &Bb[((rb) + 16 + fr) * 64];           \
        d00 = *(const bf16x8*)(_q0 + KO0); d01 = *(const bf16x8*)(_q0 + KO1); \
        d10 = *(const bf16x8*)(_q1 + KO0); d11 = *(const bf16x8*)(_q1 + KO1); \
    } while (0)

// 16 MFMAs: acc rows ti0..ti0+3, cols tj0..tj0+1; ks=0 batch then ks=1 batch.
#define MMA_Q(ti0, tj0, B00, B01, B10, B11) do {                          \
        acc[(ti0)  ][(tj0)  ] = MF(Fa00, B00, acc[(ti0)  ][(tj0)  ]);     \
        acc[(ti0)  ][(tj0)+1] = MF(Fa00, B10, acc[(ti0)  ][(tj0)+1]);     \
        acc[(ti0)+1][(tj0)  ] = MF(Fa10, B00, acc[(ti0)+1][(tj0)  ]);     \
        acc[(ti0)+1][(tj0)+1] = MF(Fa10, B10, acc[(ti0)+1][(tj0)+1]);     \
        acc[(ti0)+2][(tj0)  ] = MF(Fa20, B00, acc[(ti0)+2][(tj0)  ]);     \
        acc[(ti0)+2][(tj0)+1] = MF(Fa20, B10, acc[(ti0)+2][(tj0)+1]);     \
        acc[(ti0)+3][(tj0)  ] = MF(Fa30, B00, acc[(ti0)+3][(tj0)  ]);     \
        acc[(ti0)+3][(tj0)+1] = MF(Fa30, B10, acc[(ti0)+3][(tj0)+1]);     \
        acc[(ti0)  ][(tj0)  ] = MF(Fa01, B01, acc[(ti0)  ][(tj0)  ]);     \
        acc[(ti0)  ][(tj0)+1] = MF(Fa01, B11, acc[(ti0)  ][(tj0)+1]);     \
        acc[(ti0)+1][(tj0)  ] = MF(Fa11, B01, acc[(ti0)+1][(tj0)  ]);     \
        acc[(ti0)+1][(tj0)+1] = MF(Fa11, B11, acc[(ti0)+1][(tj0)+1]);     \
        acc[(ti0)+2][(tj0)  ] = MF(Fa21, B01, acc[(ti0)+2][(tj0)  ]);     \
        acc[(ti0)+2][(tj0)+1] = MF(Fa21, B11, acc[(ti0)+2][(tj0)+1]);     \
        acc[(ti0)+3][(tj0)  ] = MF(Fa31, B01, acc[(ti0)+3][(tj0)  ]);     \
        acc[(ti0)+3][(tj0)+1] = MF(Fa31, B11, acc[(ti0)+3][(tj0)+1]);     \
    } while (0)

    // ---- prologue: tile0 full + tile1 {B0,B1,A0}; A1 of tile1 is staged in T=0 ph1 ----
    STAGE(Ag00, Ag01, As0, 0,    0); STAGE(Ag10, Ag11, As0, 8192, 0);
    STAGE(Bg00, Bg01, Bs0, 0,    0); STAGE(Bg10, Bg11, Bs0, 8192, 0);
    STAGE(Bg00, Bg01, Bs1, 0,    1); STAGE(Bg10, Bg11, Bs1, 8192, 1);
    STAGE(Ag00, Ag01, As1, 0,    1);
    VMCNT(6);                                     // tile0 resident; 3 halves in flight
    BARR();

    for (int T = 0; T < NT; ++T) {
        const int pb = T & 1;
        unsigned short* const Ab  = smem + pb * 32768;
        unsigned short* const Bb  = Ab + 16384;
        unsigned short* const Anx = smem + (pb ^ 1) * 32768;

        // ---- phase 1: q0 = A-lo x B-lo ----
        LOAD_A_HALF(wr);
        LOAD_B_PAIR(Fb00, Fb01, Fb10, Fb11, wc);
        if (T + 1 < NT) STAGE(Ag10, Ag11, Anx, 8192, T + 1);
        BARR(); LGKM0();
        __builtin_amdgcn_s_setprio(1);
        MMA_Q(0, 0, Fb00, Fb01, Fb10, Fb11);
        __builtin_amdgcn_s_setprio(0);
        BARR();

        // ---- phase 2: q1 = A-lo x B-hi ----
        LOAD_B_PAIR(Fc00, Fc01, Fc10, Fc11, wc + 32);
        BARR(); LGKM0();
        __builtin_amdgcn_s_setprio(1);
        MMA_Q(0, 2, Fc00, Fc01, Fc10, Fc11);
        __builtin_amdgcn_s_setprio(0);
        BARR();

        // ---- phase 3: q2 = A-hi x B-lo ----
        LOAD_A_HALF(wr + 64);
        if (T + 2 < NT) STAGE(Bg00, Bg01, Bb, 0, T + 2);   // whole B dead since ph2-end
        BARR(); LGKM0();
        __builtin_amdgcn_s_setprio(1);
        MMA_Q(4, 0, Fb00, Fb01, Fb10, Fb11);
        __builtin_amdgcn_s_setprio(0);
        BARR();

        // ---- phase 4: q3 = A-hi x B-hi ----
        if (T + 2 < NT) { STAGE(Bg10, Bg11, Bb, 8192, T + 2); STAGE(Ag00, Ag01, Ab, 0, T + 2); }
        if (T + 2 < NT)      { VMCNT(6); }         // forces all of tile T+1 resident
        else if (T + 1 < NT) { VMCNT(0); }         // last prefetched tile: full drain
        BARR(); LGKM0();
        __builtin_amdgcn_s_setprio(1);
        MMA_Q(4, 2, Fc00, Fc01, Fc10, Fc11);
        __builtin_amdgcn_s_setprio(0);
        BARR();
    }
#undef STAGE
#undef LOAD_A_HALF
#undef LOAD_B_PAIR
#undef MMA_Q

    // C/D layout: col = lane&15, row = (lane>>4)*4 + reg
    const int crow = fq * 4;
    const int ccol = fr;

    if (OUT_BF16) {
        VMCNT(0);                                  // nothing should be in flight; belt+braces
        unsigned short* Cs = smem;                 // [128][264] per half
#define ST1(ti, tj, r) Cs[((ti)*16 + crow + (r))*264 + wc + (tj)*16 + ccol] = \
        f2us(act<EPI>(acc[ti][tj][r]))
#define ST_TJ(ti, tj) ST1(ti, tj, 0); ST1(ti, tj, 1); ST1(ti, tj, 2); ST1(ti, tj, 3)
#define ST_TI(ti) ST_TJ(ti, 0); ST_TJ(ti, 1); ST_TJ(ti, 2); ST_TJ(ti, 3)
        // ---- half 0 (rows m0..m0+127): waves wr==0 hold all of it ----
        if (wr == 0) {
            ST_TI(0); ST_TI(1); ST_TI(2); ST_TI(3); ST_TI(4); ST_TI(5); ST_TI(6); ST_TI(7);
        }
        LGKM0(); BARR();
        {
            const int row = tid >> 2, cb = (tid & 3) << 6;
            const unsigned short* src = &Cs[row * 264 + cb];
            unsigned short* dst = (unsigned short*)Cv + (size_t)(m0 + row) * N + n0 + cb;
#pragma unroll
            for (int j = 0; j < 8; ++j)
                *(uint4*)(dst + j * 8) = *(const uint4*)(src + j * 8);
        }
        BARR();
        // ---- half 1 (rows m0+128..m0+255): waves wr==128 ----
        if (wr == 128) {
            ST_TI(0); ST_TI(1); ST_TI(2); ST_TI(3); ST_TI(4); ST_TI(5); ST_TI(6); ST_TI(7);
        }
        LGKM0(); BARR();
        {
            const int row = tid >> 2, cb = (tid & 3) << 6;
            const unsigned short* src = &Cs[row * 264 + cb];
            unsigned short* dst = (unsigned short*)Cv + (size_t)(m0 + 128 + row) * N + n0 + cb;
#pragma unroll
            for (int j = 0; j < 8; ++j)
                *(uint4*)(dst + j * 8) = *(const uint4*)(src + j * 8);
        }
#undef ST1
#undef ST_TJ
#undef ST_TI
    } else {
        float* C = (float*)Cv;
#define STF1(ti, tj, r) C[(size_t)(m0 + wr + (ti)*16 + crow + (r)) * N + n0 + wc + (tj)*16 + ccol] = \
        act<EPI>(acc[ti][tj][r])
#define STF_TJ(ti, tj) STF1(ti, tj, 0); STF1(ti, tj, 1); STF1(ti, tj, 2); STF1(ti, tj, 3)
#define STF_TI(ti) STF_TJ(ti, 0); STF_TJ(ti, 1); STF_TJ(ti, 2); STF_TJ(ti, 3)
        STF_TI(0); STF_TI(1); STF_TI(2); STF_TI(3); STF_TI(4); STF_TI(5); STF_TI(6); STF_TI(7);
#undef STF1
#undef STF_TJ
#undef STF_TI
    }
#undef MF
#undef KO0
#undef KO1
}

// =============== GLA pass A1: decays + scores + intra (per chunk,bh) ===============
__global__ __launch_bounds__(256) void gla_a1(unsigned short* __restrict__ qb,
                                              unsigned short* __restrict__ lfb,
                                              const unsigned short* __restrict__ vb,
                                              unsigned short* __restrict__ obf,
                                              float* __restrict__ dbuf)
{
    __shared__ unsigned short q_sh[64][136];
    __shared__ unsigned short kd_sh[64][136];
    __shared__ unsigned short vT[128][72];   // v^T [f][t]
    __shared__ unsigned short sc[64][72];    // scores [t][s]

    const int tid = threadIdx.x;
    const int bid = blockIdx.x;
    const int c = bid >> 6, bh = bid & 63;
    const int b = bh >> 4, h = bh & 15;
    const size_t tok0 = ((size_t)b * 4096 + (size_t)c * 64) * 2048 + (size_t)h * 128;

#pragma unroll
    for (int k = 0; k < 4; ++k) {
        int vi = tid + k * 256;
        int t = vi >> 4, e8 = (vi & 15) << 3;
        *(uint4*)&q_sh[t][e8]  = *(const uint4*)(qb  + tok0 + (size_t)t * 2048 + e8);
        *(uint4*)&kd_sh[t][e8] = *(const uint4*)(lfb + tok0 + (size_t)t * 2048 + e8);
    }
    if (tid < 128) {
        int t8 = tid >> 4, f8 = tid & 15;
        __align__(16) unsigned short a[8][8];
#pragma unroll
        for (int r = 0; r < 8; ++r)
            *(uint4*)a[r] = *(const uint4*)(vb + tok0 + (size_t)(t8 * 8 + r) * 2048 + f8 * 8);
#pragma unroll
        for (int j = 0; j < 8; ++j) {
            __align__(16) unsigned short w8[8];
#pragma unroll
            for (int r = 0; r < 8; ++r) w8[r] = a[r][j];
            *(uint4*)&vT[f8 * 8 + j][t8 * 8] = *(const uint4*)w8;
        }
    }
    __syncthreads();
    if (tid < 128) {
        const int e = tid;
        float a = 0.f;
        for (int t = 0; t < 64; ++t) {
            float lf = us2f(kd_sh[t][e]);
            a += lf;
            q_sh[t][e]  = f2us(us2f(q_sh[t][e]) * __expf(a));       // q_dec
            kd_sh[t][e] = f2us((1.f - __expf(lf)) * __expf(-a));    // k_dec
        }
        dbuf[(size_t)bid * 128 + e] = __expf(a);
    }
    __syncthreads();
#pragma unroll
    for (int k = 0; k < 4; ++k) {
        int vi = tid + k * 256;
        int t = vi >> 4, e8 = (vi & 15) << 3;
        *(uint4*)(qb  + tok0 + (size_t)t * 2048 + e8) = *(const uint4*)&q_sh[t][e8];
        *(uint4*)(lfb + tok0 + (size_t)t * 2048 + e8) = *(const uint4*)&kd_sh[t][e8];
    }

    const int lane = tid & 63, w = tid >> 6;
    const int fr = lane & 15, fq = lane >> 4;

    // scores = qdec @ kdec^T
    f32x4 sacc[4];
#pragma unroll
    for (int j = 0; j < 4; ++j) sacc[j] = (f32x4){0.f, 0.f, 0.f, 0.f};
#pragma unroll
    for (int ke = 0; ke < 4; ++ke) {
        bf16x8 af = *(const bf16x8*)&q_sh[16 * w + fr][ke * 32 + fq * 8];
#pragma unroll
        for (int tj = 0; tj < 4; ++tj) {
            bf16x8 bfv = *(const bf16x8*)&kd_sh[16 * tj + fr][ke * 32 + fq * 8];
            sacc[tj] = __builtin_amdgcn_mfma_f32_16x16x32_bf16(af, bfv, sacc[tj], 0, 0, 0);
        }
    }
#pragma unroll
    for (int tj = 0; tj < 4; ++tj)
#pragma unroll
        for (int r = 0; r < 4; ++r) {
            int trow = 16 * w + fq * 4 + r;
            int scol = 16 * tj + fr;
            sc[trow][scol] = f2us(scol <= trow ? sacc[tj][r] : 0.f);
        }
    __syncthreads();
    // intra = sc @ v
    f32x4 oacc[8];
#pragma unroll
    for (int j = 0; j < 8; ++j) oacc[j] = (f32x4){0.f, 0.f, 0.f, 0.f};
#pragma unroll
    for (int ks = 0; ks < 2; ++ks) {
        bf16x8 af = *(const bf16x8*)&sc[16 * w + fr][ks * 32 + fq * 8];
#pragma unroll
        for (int tf = 0; tf < 8; ++tf) {
            bf16x8 bfv = *(const bf16x8*)&vT[16 * tf + fr][ks * 32 + fq * 8];
            oacc[tf] = __builtin_amdgcn_mfma_f32_16x16x32_bf16(af, bfv, oacc[tf], 0, 0, 0);
        }
    }
#pragma unroll
    for (int tf = 0; tf < 8; ++tf) {
        __align__(8) unsigned short o4[4];
#pragma unroll
        for (int r = 0; r < 4; ++r) o4[r] = f2us(oacc[tf][r]);
        *(uint2*)(obf + (((size_t)bid * 4 + w) * 8 + tf) * 256 + lane * 4) = *(const uint2*)o4;
    }
}

// =============== GLA pass A2: U^T[f][e] = d[e] * sum_t kdec[t][e] v[t][f] ===============
__global__ __launch_bounds__(256) void gla_a2(const unsigned short* __restrict__ lfb, // kdec
                                              const unsigned short* __restrict__ vb,
                                              const float* __restrict__ dbuf,
                                              unsigned short* __restrict__ UT)
{
    __shared__ unsigned short vT[128][72];
    __shared__ unsigned short kdT[128][72];
    __shared__ float d_sh[128];

    const int tid = threadIdx.x;
    const int bid = blockIdx.x;
    const int c = bid >> 6, bh = bid & 63;
    const int b = bh >> 4, h = bh & 15;
    const size_t tok0 = ((size_t)b * 4096 + (size_t)c * 64) * 2048 + (size_t)h * 128;

    if (tid < 128) {
        int t8 = tid >> 4, f8 = tid & 15;
        __align__(16) unsigned short a[8][8];
#pragma unroll
        for (int r = 0; r < 8; ++r)
            *(uint4*)a[r] = *(const uint4*)(vb + tok0 + (size_t)(t8 * 8 + r) * 2048 + f8 * 8);
#pragma unroll
        for (int j = 0; j < 8; ++j) {
            __align__(16) unsigned short w8[8];
#pragma unroll
            for (int r = 0; r < 8; ++r) w8[r] = a[r][j];
            *(uint4*)&vT[f8 * 8 + j][t8 * 8] = *(const uint4*)w8;
        }
        d_sh[tid] = dbuf[(size_t)bid * 128 + tid];
    } else {
        int i = tid - 128;
        int t8 = i >> 4, e8b = i & 15;
        __align__(16) unsigned short a[8][8];
#pragma unroll
        for (int r = 0; r < 8; ++r)
            *(uint4*)a[r] = *(const uint4*)(lfb + tok0 + (size_t)(t8 * 8 + r) * 2048 + e8b * 8);
#pragma unroll
        for (int j = 0; j < 8; ++j) {
            __align__(16) unsigned short w8[8];
#pragma unroll
            for (int r = 0; r < 8; ++r) w8[r] = a[r][j];
            *(uint4*)&kdT[e8b * 8 + j][t8 * 8] = *(const uint4*)w8;
        }
    }
    __syncthreads();

    const int lane = tid & 63, w = tid >> 6;
    const int fr = lane & 15, fq = lane >> 4;

    f32x4 acc[2][8];
#pragma unroll
    for (int mi = 0; mi < 2; ++mi)
#pragma unroll
        for (int te = 0; te < 8; ++te) acc[mi][te] = (f32x4){0.f, 0.f, 0.f, 0.f};
#pragma unroll
    for (int kt = 0; kt < 2; ++kt) {
        bf16x8 af0 = *(const bf16x8*)&vT[16 * (2 * w + 0) + fr][kt * 32 + fq * 8];
        bf16x8 af1 = *(const bf16x8*)&vT[16 * (2 * w + 1) + fr][kt * 32 + fq * 8];
#pragma unroll
        for (int te = 0; te < 8; ++te) {
            bf16x8 bfv = *(const bf16x8*)&kdT[16 * te + fr][kt * 32 + fq * 8];
            acc[0][te] = __builtin_amdgcn_mfma_f32_16x16x32_bf16(af0, bfv, acc[0][te], 0, 0, 0);
            acc[1][te] = __builtin_amdgcn_mfma_f32_16x16x32_bf16(af1, bfv, acc[1][te], 0, 0, 0);
        }
    }
    unsigned short* up = UT + (size_t)bid * 16384;
#pragma unroll
    for (int mi = 0; mi < 2; ++mi)
#pragma unroll
        for (int te = 0; te < 8; ++te) {
            int e = 16 * te + fr;
            float dv = d_sh[e];
#pragma unroll
            for (int r = 0; r < 4; ++r) {
                int f = 32 * w + 16 * mi + fq * 4 + r;
                up[f * 128 + e] = f2us(acc[mi][te][r] * dv);
            }
        }
}

// =============== GLA pass B: in-place scan UT[c] -> S-before-chunk-c ===============
__global__ __launch_bounds__(256) void gla_scan(unsigned short* __restrict__ UT,
                                                const float* __restrict__ dbuf)
{
    const int tid = threadIdx.x;
    const int bh = blockIdx.x >> 3, fs = blockIdx.x & 7;
    const int f = fs * 16 + (tid >> 4);
    const int e8 = (tid & 15) << 3;
    float S[8];
#pragma unroll
    for (int j = 0; j < 8; ++j) S[j] = 0.f;
    for (int c = 0; c < 64; ++c) {
        const size_t cb = (size_t)(c * 64 + bh);
        const size_t loc = cb * 16384 + (size_t)f * 128 + e8;
        uint4 uu = *(const uint4*)(UT + loc);
        float4 d0 = *(const float4*)(dbuf + cb * 128 + e8);
        float4 d1 = *(const float4*)(dbuf + cb * 128 + e8 + 4);
        __align__(16) unsigned short us8[8];
        *(uint4*)us8 = uu;
        __align__(16) unsigned short so[8];
#pragma unroll
        for (int j = 0; j < 8; ++j) so[j] = f2us(S[j]);
        *(uint4*)(UT + loc) = *(const uint4*)so;
        float dd[8] = {d0.x, d0.y, d0.z, d0.w, d1.x, d1.y, d1.z, d1.w};
#pragma unroll
        for (int j = 0; j < 8; ++j) S[j] = fmaf(dd[j], S[j], us2f(us8[j]));
    }
}

// =============== GLA pass C: o = intra + qdec @ S^T; write o over qb ===============
__global__ __launch_bounds__(256) void gla_c(unsigned short* __restrict__ qb,
                                             const unsigned short* __restrict__ UT, // = S^T[f][e]
                                             const unsigned short* __restrict__ obf)
{
    __shared__ unsigned short q_sh[64][136];
    __shared__ unsigned short ST_sh[128][136];

    const int tid = threadIdx.x;
    const int bid = blockIdx.x;
    const int c = bid >> 6, bh = bid & 63;
    const int b = bh >> 4, h = bh & 15;
    const size_t tok0 = ((size_t)b * 4096 + (size_t)c * 64) * 2048 + (size_t)h * 128;

#pragma unroll
    for (int k = 0; k < 4; ++k) {
        int vi = tid + k * 256;
        int t = vi >> 4, e8 = (vi & 15) << 3;
        *(uint4*)&q_sh[t][e8] = *(const uint4*)(qb + tok0 + (size_t)t * 2048 + e8);
    }
    const unsigned short* stp = UT + (size_t)bid * 16384;
#pragma unroll
    for (int k = 0; k < 8; ++k) {
        int vi = tid + k * 256;
        int f = vi >> 4, e8 = (vi & 15) << 3;
        *(uint4*)&ST_sh[f][e8] = *(const uint4*)(stp + (size_t)f * 128 + e8);
    }
    const int lane = tid & 63, w = tid >> 6;
    const int fr = lane & 15, fq = lane >> 4;

    f32x4 acc[8];
#pragma unroll
    for (int tf = 0; tf < 8; ++tf) {
        uint2 iv = *(const uint2*)(obf + (((size_t)bid * 4 + w) * 8 + tf) * 256 + lane * 4);
        __align__(8) unsigned short s4[4];
        *(uint2*)s4 = iv;
        acc[tf] = (f32x4){us2f(s4[0]), us2f(s4[1]), us2f(s4[2]), us2f(s4[3])};
    }
    __syncthreads();
#pragma unroll
    for (int ke = 0; ke < 4; ++ke) {
        bf16x8 af = *(const bf16x8*)&q_sh[16 * w + fr][ke * 32 + fq * 8];
#pragma unroll
        for (int tf = 0; tf < 8; ++tf) {
            bf16x8 bfv = *(const bf16x8*)&ST_sh[16 * tf + fr][ke * 32 + fq * 8];
            acc[tf] = __builtin_amdgcn_mfma_f32_16x16x32_bf16(af, bfv, acc[tf], 0, 0, 0);
        }
    }
#pragma unroll
    for (int tf = 0; tf < 8; ++tf)
#pragma unroll
        for (int r = 0; r < 4; ++r) {
            int t = 16 * w + fq * 4 + r;
            qb[tok0 + (size_t)t * 2048 + 16 * tf + fr] = f2us(acc[tf][r]);
        }
}

// =============== RMSNorm (in-place, bf16) ===============
__global__ __launch_bounds__(256) void rmsnorm_kernel(unsigned short* __restrict__ o,
                                                      const float* __restrict__ w)
{
    __shared__ float red[4];
    const int row = blockIdx.x;
    const int tid = threadIdx.x;
    unsigned short* p = o + (size_t)row * 2048 + tid * 8;
    __align__(16) unsigned short u[8];
    *(uint4*)u = *(const uint4*)p;
    float f[8];
    float ss = 0.f;
#pragma unroll
    for (int j = 0; j < 8; ++j) { f[j] = us2f(u[j]); ss = fmaf(f[j], f[j], ss); }
#pragma unroll
    for (int off = 32; off > 0; off >>= 1) ss += __shfl_down(ss, off, 64);
    if ((tid & 63) == 0) red[tid >> 6] = ss;
    __syncthreads();
    float tot = red[0] + red[1] + red[2] + red[3];
    float scale = rsqrtf(tot * (1.f / 2048.f) + 1e-6f);
    const float* wp = w + tid * 8;
#pragma unroll
    for (int j = 0; j < 8; ++j) u[j] = f2us(f[j] * scale * wp[j]);
    *(uint4*)p = *(const uint4*)u;
}

extern "C" void kernel_launch(void* const* d_in, const int* in_sizes, int n_in,
                              void* d_out, int out_size, void* d_ws, size_t ws_size,
                              hipStream_t stream)
{
    const float* x  = (const float*)d_in[0];
    const float* Wq = (const float*)d_in[1];
    const float* Wk = (const float*)d_in[2];
    const float* Wv = (const float*)d_in[3];
    const float* Wo = (const float*)d_in[4];
    const float* nw = (const float*)d_in[5];
    float* out = (float*)d_out;

    const int M = 16384, N = 2048, K = 2048;
    const size_t S1 = (size_t)M * N;
    const size_t SW = (size_t)N * K;
    const size_t UTsz = (size_t)4096 * 16384;

    unsigned short* xb  = (unsigned short*)d_ws;
    unsigned short* Wqb = xb + S1;
    unsigned short* Wkb = Wqb + SW;
    unsigned short* Wvb = Wkb + SW;
    unsigned short* Wob = Wvb + SW;
    unsigned short* qb  = Wob + SW;   // q -> qdec -> o
    unsigned short* vbf = qb + S1;
    unsigned short* lfb = vbf + S1;   // log_f -> kdec
    unsigned short* obf = lfb + S1;   // intra frags
    unsigned short* UT  = obf + S1;   // U^T then S^T (in-place scan)
    float* dbuf = (float*)(UT + UTsz);

    cast_bf16<<<(int)(S1 / 8 / 256), 256, 0, stream>>>(x, xb, (int)(S1 / 8));
    cast_bf16<<<(int)(SW / 8 / 256), 256, 0, stream>>>(Wq, Wqb, (int)(SW / 8));
    cast_bf16<<<(int)(SW / 8 / 256), 256, 0, stream>>>(Wk, Wkb, (int)(SW / 8));
    cast_bf16<<<(int)(SW / 8 / 256), 256, 0, stream>>>(Wv, Wvb, (int)(SW / 8));
    cast_bf16<<<(int)(SW / 8 / 256), 256, 0, stream>>>(Wo, Wob, (int)(SW / 8));

    dim3 gg(M / 256, N / 256);  // x fastest => same-n0 tiles consecutive; A-panel reuse same-XCD (64%8==0)
    gemm_bt_mfma<EPI_SILU,  true><<<gg, 512, 0, stream>>>(xb, Wqb, qb,  M, N, K);
    gemm_bt_mfma<EPI_LOGSIG,true><<<gg, 512, 0, stream>>>(xb, Wkb, lfb, M, N, K);
    gemm_bt_mfma<EPI_NONE,  true><<<gg, 512, 0, stream>>>(xb, Wvb, vbf, M, N, K);

    gla_a1<<<4096, 256, 0, stream>>>(qb, lfb, vbf, obf, dbuf);
    gla_a2<<<4096, 256, 0, stream>>>(lfb, vbf, dbuf, UT);
    gla_scan<<<512, 256, 0, stream>>>(UT, dbuf);
    gla_c<<<4096, 256, 0, stream>>>(qb, UT, obf);

    rmsnorm_kernel<<<16384, 256, 0, stream>>>(qb, nw);
    gemm_bt_mfma<EPI_NONE, false><<<gg, 512, 0, stream>>>(qb, Wob, out, M, N, K);
}